// Round 3
// baseline (177.512 us; speedup 1.0000x reference)
//
#include <hip/hip_runtime.h>

typedef float f32x4 __attribute__((ext_vector_type(4)));
typedef short bf16x8 __attribute__((ext_vector_type(8)));
typedef unsigned int u32;
typedef unsigned short u16;

constexpr int T_ = 32768;
constexpr int D_ = 2048;
constexpr int E_ = 64;
constexpr int KSEL = 6;
constexpr float ROUTE_SCALE_ = 1.0f;

constexpr int ROWS = 128;              // rows per block (4 waves x 32)
constexpr int DK = 32;                 // k per chunk
constexpr int NCH = D_ / DK;           // 64
constexpr int XBYTES = ROWS * DK * 4;  // 16384 (fp32 x tile)
constexpr int WBYTES = 3 * E_ * DK * 2;// 12288 (3 bf16 planes of W)
constexpr int BUFB = XBYTES + WBYTES;  // 28672
constexpr int LGT_OFF = 4 * BUFB;      // 114688; +32KB logits = 147456 LDS

__device__ __forceinline__ u16 f2bf(float f) {
  u32 u = __float_as_uint(f);
  return (u16)((u + 0x7fffu + ((u >> 16) & 1u)) >> 16);
}
__device__ __forceinline__ float bf2f(u16 h) { return __uint_as_float(((u32)h) << 16); }

// ---- W pre-split: [64e][2048k] fp32 -> ws[c][p][e][32k] bf16, k-slot16 XOR-swizzled ----
__global__ void wsplit_kernel(const float* __restrict__ W, u16* __restrict__ ws) {
  int idx = blockIdx.x * 256 + threadIdx.x;   // 16384 = e(64) * c(64) * slot(4)
  int slot = idx & 3, c = (idx >> 2) & 63, e = idx >> 8;
  const float* src = W + (size_t)e * D_ + c * 32 + slot * 8;
  f32x4 a0 = *(const f32x4*)src;
  f32x4 a1 = *(const f32x4*)(src + 4);
  float f[8] = {a0.x, a0.y, a0.z, a0.w, a1.x, a1.y, a1.z, a1.w};
  u16 h[8], m[8], l[8];
#pragma unroll
  for (int j = 0; j < 8; ++j) {
    h[j] = f2bf(f[j]);  float r1 = f[j] - bf2f(h[j]);
    m[j] = f2bf(r1);    float r2 = r1 - bf2f(m[j]);
    l[j] = f2bf(r2);
  }
  int slot_s = slot ^ ((e >> 1) & 3);
  u16* dst = ws + (size_t)c * 6144 + (size_t)e * 32 + slot_s * 8;
  typedef u16 u16x8 __attribute__((ext_vector_type(8)));
  *(u16x8*)(dst)        = *(u16x8*)h;
  *(u16x8*)(dst + 2048) = *(u16x8*)m;
  *(u16x8*)(dst + 4096) = *(u16x8*)l;
}

__device__ __forceinline__ void gload16(const void* g, void* l) {
  __builtin_amdgcn_global_load_lds(
      (const __attribute__((address_space(1))) void*)g,
      (__attribute__((address_space(3))) void*)l, 16, 0, 0);
}

__launch_bounds__(256, 1)
__global__ void gate_kernel(const float* __restrict__ x, const u16* __restrict__ ws,
                            float* __restrict__ out) {
  __shared__ __align__(16) char sm[LGT_OFF + ROWS * E_ * 4];  // 147456 B

  const int tid = threadIdx.x;
  const int lane = tid & 63;
  const int wv = tid >> 6;          // 0..3
  const int el = lane & 15;
  const int kg = lane >> 4;         // 0..3
  const int r0 = blockIdx.x * ROWS;

  // x staging source (inverse-swizzled so LDS image is row*128 + (k16^(row&7))*16)
  const int row_l = tid >> 3;                       // 0..31
  const int k16s = (tid & 7) ^ (row_l & 7);
  const char* xsrc0 = (const char*)x + (size_t)(r0 + row_l) * D_ * 4 + k16s * 16;
  const char* wbase = (const char*)ws;

  auto stage = [&](int bi, int ch) {
    const char* xs = xsrc0 + (size_t)ch * 128;
    const int xb = bi * BUFB;
#pragma unroll
    for (int it = 0; it < 4; ++it)
      gload16(xs + (size_t)it * 32 * D_ * 4, &sm[xb + (it * 256 + wv * 64) * 16]);
    const char* wsrc = wbase + (size_t)ch * WBYTES + (size_t)tid * 16;
#pragma unroll
    for (int it = 0; it < 3; ++it)
      gload16(wsrc + it * 4096, &sm[xb + XBYTES + (it * 256 + wv * 64) * 16]);
  };

  // ds_read addresses (iter-invariant parts)
  const int aoff0 = (wv * 32 + el) * 128 + (((2 * kg + 0) ^ (el & 7)) * 16);
  const int aoff1 = (wv * 32 + el) * 128 + (((2 * kg + 1) ^ (el & 7)) * 16);
  const int boff = XBYTES + el * 64 + ((kg ^ ((el >> 1) & 3)) * 16);

  f32x4 acc[2][4] = {};

  auto compute = [&](int bufbase) {
    union { u32 w[4]; bf16x8 v; } ah[2], am[2], al[2];
#pragma unroll
    for (int mf = 0; mf < 2; ++mf) {
      f32x4 a0 = *(const f32x4*)&sm[bufbase + aoff0 + mf * 2048];
      f32x4 a1 = *(const f32x4*)&sm[bufbase + aoff1 + mf * 2048];
      float f[8] = {a0.x, a0.y, a0.z, a0.w, a1.x, a1.y, a1.z, a1.w};
#pragma unroll
      for (int j = 0; j < 4; ++j) {
        float f0 = f[2 * j], f1 = f[2 * j + 1];
        u32 ph; asm("v_cvt_pk_bf16_f32 %0, %1, %2" : "=v"(ph) : "v"(f0), "v"(f1));
        float h0 = __uint_as_float(ph << 16), h1 = __uint_as_float(ph & 0xffff0000u);
        float r0f = f0 - h0, r1f = f1 - h1;
        u32 pm; asm("v_cvt_pk_bf16_f32 %0, %1, %2" : "=v"(pm) : "v"(r0f), "v"(r1f));
        float m0 = __uint_as_float(pm << 16), m1 = __uint_as_float(pm & 0xffff0000u);
        float s0 = r0f - m0, s1 = r1f - m1;
        u32 pl; asm("v_cvt_pk_bf16_f32 %0, %1, %2" : "=v"(pl) : "v"(s0), "v"(s1));
        ah[mf].w[j] = ph; am[mf].w[j] = pm; al[mf].w[j] = pl;
      }
    }
#pragma unroll
    for (int nf = 0; nf < 4; ++nf) {
      bf16x8 bh = *(const bf16x8*)&sm[bufbase + boff + 0 * 4096 + nf * 1024];
      bf16x8 bm = *(const bf16x8*)&sm[bufbase + boff + 1 * 4096 + nf * 1024];
      bf16x8 bl = *(const bf16x8*)&sm[bufbase + boff + 2 * 4096 + nf * 1024];
#pragma unroll
      for (int mf = 0; mf < 2; ++mf) {
        f32x4 c = acc[mf][nf];
        c = __builtin_amdgcn_mfma_f32_16x16x32_bf16(al[mf].v, bh, c, 0, 0, 0);
        c = __builtin_amdgcn_mfma_f32_16x16x32_bf16(am[mf].v, bm, c, 0, 0, 0);
        c = __builtin_amdgcn_mfma_f32_16x16x32_bf16(ah[mf].v, bl, c, 0, 0, 0);
        c = __builtin_amdgcn_mfma_f32_16x16x32_bf16(am[mf].v, bh, c, 0, 0, 0);
        c = __builtin_amdgcn_mfma_f32_16x16x32_bf16(ah[mf].v, bm, c, 0, 0, 0);
        c = __builtin_amdgcn_mfma_f32_16x16x32_bf16(ah[mf].v, bh, c, 0, 0, 0);
        acc[mf][nf] = c;
      }
    }
  };

  // prologue: stage chunks 0,1; in-loop: stage ch+2, wait chunk ch (allow 14 in flight)
  stage(0, 0);
  stage(1, 1);
  for (int ch = 0; ch < NCH - 2; ++ch) {
    stage((ch + 2) & 3, ch + 2);
    asm volatile("s_waitcnt vmcnt(14)" ::: "memory");
    __builtin_amdgcn_s_barrier();
    compute((ch & 3) * BUFB);
  }
  asm volatile("s_waitcnt vmcnt(7)" ::: "memory");
  __builtin_amdgcn_s_barrier();
  compute(((NCH - 2) & 3) * BUFB);
  asm volatile("s_waitcnt vmcnt(0)" ::: "memory");
  __builtin_amdgcn_s_barrier();
  compute(((NCH - 1) & 3) * BUFB);

  // dump logits (C/D: col=lane&15, row=(lane>>4)*4+j) — wave-local region, no barrier
  float* LGT = (float*)&sm[LGT_OFF];
#pragma unroll
  for (int mf = 0; mf < 2; ++mf)
#pragma unroll
    for (int nf = 0; nf < 4; ++nf)
#pragma unroll
      for (int j = 0; j < 4; ++j) {
        int r = wv * 32 + mf * 16 + (lane >> 4) * 4 + j;
        int e = nf * 16 + el;
        LGT[r * 64 + e] = acc[mf][nf][j];
      }

  // top-k epilogue (verified R1/R2): lane = expert, 32 rows per wave
  float* outI = out;
  float* outW = out + (size_t)T_ * KSEL;
  for (int rr = 0; rr < 32; ++rr) {
    const int r = wv * 32 + rr;
    const float lg = LGT[r * 64 + lane];
    float mx = lg;
#pragma unroll
    for (int off = 32; off; off >>= 1) mx = fmaxf(mx, __shfl_xor(mx, off, 64));
    const float p = expf(lg - mx);
    float ssum = p;
#pragma unroll
    for (int off = 32; off; off >>= 1) ssum += __shfl_xor(ssum, off, 64);
    float prob = p / ssum;

    const int rg = r0 + r;
#pragma unroll
    for (int kk = 0; kk < KSEL; ++kk) {
      float v = prob; int idx = lane;
#pragma unroll
      for (int off = 32; off; off >>= 1) {
        float ov = __shfl_xor(v, off, 64);
        int oi = __shfl_xor(idx, off, 64);
        if (ov > v || (ov == v && oi < idx)) { v = ov; idx = oi; }
      }
      const float wsel = __shfl(lg, idx, 64);
      if (lane == 0) {
        outI[(size_t)rg * KSEL + kk] = (float)idx;
        outW[(size_t)rg * KSEL + kk] = wsel * ROUTE_SCALE_;
      }
      if (lane == idx) prob = -1.0f;
    }
  }
}

extern "C" void kernel_launch(void* const* d_in, const int* in_sizes, int n_in,
                              void* d_out, int out_size, void* d_ws, size_t ws_size,
                              hipStream_t stream) {
  const float* x = (const float*)d_in[0];
  const float* W = (const float*)d_in[1];
  u16* ws = (u16*)d_ws;   // needs 64*12288 = 786432 bytes
  float* out = (float*)d_out;
  wsplit_kernel<<<dim3(64), dim3(256), 0, stream>>>(W, ws);
  gate_kernel<<<dim3(T_ / ROWS), dim3(256), 0, stream>>>(x, ws, out);
}

// Round 4
// 174.078 us; speedup vs baseline: 1.0197x; 1.0197x over previous
//
#include <hip/hip_runtime.h>

typedef float f32x4 __attribute__((ext_vector_type(4)));
typedef short bf16x8 __attribute__((ext_vector_type(8)));
typedef unsigned int u32;
typedef unsigned short u16;

constexpr int T_ = 32768;
constexpr int D_ = 2048;
constexpr int E_ = 64;
constexpr int KSEL = 6;
constexpr float ROUTE_SCALE_ = 1.0f;

constexpr int DK = 32;           // k per chunk
constexpr int NCH = D_ / DK;     // 64
constexpr int WROWS = 16;        // rows per wave (one 16x16x32 A frag)
constexpr int BROWS = 64;        // rows per block (4 waves)

__device__ __forceinline__ u16 f2bf(float f) {
  u32 u = __float_as_uint(f);
  return (u16)((u + 0x7fffu + ((u >> 16) & 1u)) >> 16);
}
__device__ __forceinline__ float bf2f(u16 h) { return __uint_as_float(((u32)h) << 16); }

// W pre-split into MFMA-fragment-ordered 3-plane bf16:
// frag q = (ch*4 + nf)*3 + p ; 16B per lane at ws[(q*64 + lane)*8] (u16 units).
// Element: plane_p(W[e][k]), e = nf*16 + (lane&15), k = ch*32 + (lane>>4)*8 + j.
__global__ void wsplit_kernel(const float* __restrict__ W, u16* __restrict__ ws) {
  int t = blockIdx.x * 256 + threadIdx.x;          // 16384 threads
  int lane = t & 63, nf = (t >> 6) & 3, ch = t >> 8;
  int e = nf * 16 + (lane & 15);
  int k0 = ch * 32 + ((lane >> 4) << 3);
  const float* src = W + (size_t)e * D_ + k0;
  f32x4 a0 = *(const f32x4*)src;
  f32x4 a1 = *(const f32x4*)(src + 4);
  float f[8] = {a0.x, a0.y, a0.z, a0.w, a1.x, a1.y, a1.z, a1.w};
  bf16x8 h, m, l;
#pragma unroll
  for (int j = 0; j < 8; ++j) {
    u16 hb = f2bf(f[j]); float r1 = f[j] - bf2f(hb);
    u16 mb = f2bf(r1);   float r2 = r1 - bf2f(mb);
    u16 lb = f2bf(r2);
    h[j] = (short)hb; m[j] = (short)mb; l[j] = (short)lb;
  }
  bf16x8* wp = (bf16x8*)ws;
  size_t base = (size_t)(ch * 4 + nf) * 3 * 64 + lane;
  wp[base] = h; wp[base + 64] = m; wp[base + 128] = l;
}

__launch_bounds__(256)
__global__ void gate_kernel(const float* __restrict__ x, const bf16x8* __restrict__ ws,
                            float* __restrict__ out) {
  __shared__ float LGT[BROWS * E_];   // 16 KB; wave-private 16-row slabs (no barriers)

  const int tid = threadIdx.x;
  const int lane = tid & 63;
  const int wv = tid >> 6;
  const int r0 = blockIdx.x * BROWS + wv * WROWS;   // this wave's first row

  // per-lane x address: row r0+(lane&15), k-offset (lane>>4)*8
  const float* xp = x + (size_t)(r0 + (lane & 15)) * D_ + ((lane >> 4) << 3);
  const bf16x8* wp = ws + lane;

  f32x4 acc0 = {0.f,0.f,0.f,0.f}, acc1 = acc0, acc2 = acc0, acc3 = acc0;

  f32x4 Xa[4], Xb[4];          // x fp32 slots, slot = ch & 3 (all indices static)
  bf16x8 Bf[2][12];            // B plane frags, slot = ch & 1, [nf*3 + p]

  // prologue: X chunks 0..3, B chunks 0..1
#pragma unroll
  for (int c = 0; c < 4; ++c) {
    Xa[c] = *(const f32x4*)(xp + c * 32);
    Xb[c] = *(const f32x4*)(xp + c * 32 + 4);
  }
#pragma unroll
  for (int c = 0; c < 2; ++c)
#pragma unroll
    for (int q = 0; q < 12; ++q)
      Bf[c][q] = wp[(size_t)(c * 12 + q) * 64];

  for (int cc = 0; cc < NCH; cc += 4) {
#pragma unroll
    for (int s = 0; s < 4; ++s) {
      const int ch = cc + s;
      // ---- split X slot s into 3 bf16 planes (truncation; residuals exact) ----
      f32x4 a0 = Xa[s], a1 = Xb[s];
      float f[8] = {a0.x, a0.y, a0.z, a0.w, a1.x, a1.y, a1.z, a1.w};
      bf16x8 ah, am, al;
#pragma unroll
      for (int j = 0; j < 8; ++j) {
        float v = f[j];
        u32 u  = __float_as_uint(v);
        u32 hb = u & 0xffff0000u;  float r1 = v - __uint_as_float(hb);
        u32 ub = __float_as_uint(r1);
        u32 mb = ub & 0xffff0000u; float r2 = r1 - __uint_as_float(mb);
        u32 lb = __float_as_uint(r2);
        ah[j] = (short)(hb >> 16); am[j] = (short)(mb >> 16); al[j] = (short)(lb >> 16);
      }
      // ---- prefetch X(ch+4) into slot s (issues early, lands under MFMA) ----
      if (ch + 4 < NCH) {
        Xa[s] = *(const f32x4*)(xp + (ch + 4) * 32);
        Xb[s] = *(const f32x4*)(xp + (ch + 4) * 32 + 4);
      }
      // ---- 24 MFMA with B slot (s&1); 6 products, smallest first ----
      const int bs = s & 1;
#define PROD6(ACC, NF)                                                         \
      {                                                                        \
        bf16x8 bh = Bf[bs][(NF)*3], bm = Bf[bs][(NF)*3+1], bl = Bf[bs][(NF)*3+2]; \
        ACC = __builtin_amdgcn_mfma_f32_16x16x32_bf16(al, bh, ACC, 0, 0, 0);   \
        ACC = __builtin_amdgcn_mfma_f32_16x16x32_bf16(am, bm, ACC, 0, 0, 0);   \
        ACC = __builtin_amdgcn_mfma_f32_16x16x32_bf16(ah, bl, ACC, 0, 0, 0);   \
        ACC = __builtin_amdgcn_mfma_f32_16x16x32_bf16(am, bh, ACC, 0, 0, 0);   \
        ACC = __builtin_amdgcn_mfma_f32_16x16x32_bf16(ah, bm, ACC, 0, 0, 0);   \
        ACC = __builtin_amdgcn_mfma_f32_16x16x32_bf16(ah, bh, ACC, 0, 0, 0);   \
      }
      PROD6(acc0, 0) PROD6(acc1, 1) PROD6(acc2, 2) PROD6(acc3, 3)
#undef PROD6
      // ---- prefetch B(ch+2) into slot bs (after consumption; anti-dep) ----
      if (ch + 2 < NCH) {
#pragma unroll
        for (int q = 0; q < 12; ++q)
          Bf[bs][q] = wp[(size_t)((ch + 2) * 12 + q) * 64];
      }
    }
  }

  // ---- dump logits to wave-private LDS slab (C/D: col=lane&15, row=(lane>>4)*4+j) ----
  float* slab = &LGT[wv * WROWS * E_];
#pragma unroll
  for (int j = 0; j < 4; ++j) {
    int r = ((lane >> 4) << 2) + j;
    int e = lane & 15;
    slab[r * 64 +  0 + e] = acc0[j];
    slab[r * 64 + 16 + e] = acc1[j];
    slab[r * 64 + 32 + e] = acc2[j];
    slab[r * 64 + 48 + e] = acc3[j];
  }

  // ---- top-k epilogue (verified R1-R3): lane = expert, 16 rows per wave ----
  float* outI = out;
  float* outW = out + (size_t)T_ * KSEL;
  for (int rr = 0; rr < WROWS; ++rr) {
    const float lg = slab[rr * 64 + lane];
    float mx = lg;
#pragma unroll
    for (int off = 32; off; off >>= 1) mx = fmaxf(mx, __shfl_xor(mx, off, 64));
    const float p = expf(lg - mx);
    float ssum = p;
#pragma unroll
    for (int off = 32; off; off >>= 1) ssum += __shfl_xor(ssum, off, 64);
    float prob = p / ssum;

    const int rg = r0 + rr;
#pragma unroll
    for (int kk = 0; kk < KSEL; ++kk) {
      float v = prob; int idx = lane;
#pragma unroll
      for (int off = 32; off; off >>= 1) {
        float ov = __shfl_xor(v, off, 64);
        int oi = __shfl_xor(idx, off, 64);
        if (ov > v || (ov == v && oi < idx)) { v = ov; idx = oi; }
      }
      const float wsel = __shfl(lg, idx, 64);
      if (lane == 0) {
        outI[(size_t)rg * KSEL + kk] = (float)idx;
        outW[(size_t)rg * KSEL + kk] = wsel * ROUTE_SCALE_;
      }
      if (lane == idx) prob = -1.0f;
    }
  }
}

extern "C" void kernel_launch(void* const* d_in, const int* in_sizes, int n_in,
                              void* d_out, int out_size, void* d_ws, size_t ws_size,
                              hipStream_t stream) {
  const float* x = (const float*)d_in[0];
  const float* W = (const float*)d_in[1];
  u16* ws = (u16*)d_ws;   // 64*4*3*64*16 = 786432 bytes
  float* out = (float*)d_out;
  wsplit_kernel<<<dim3(64), dim3(256), 0, stream>>>(W, ws);
  gate_kernel<<<dim3(T_ / BROWS), dim3(256), 0, stream>>>(x, (const bf16x8*)ws, out);
}